// Round 20
// baseline (306.145 us; speedup 1.0000x reference)
//
#include <hip/hip_runtime.h>
#include <hip/hip_bf16.h>
#include <hip/hip_fp8.h>
#include <math.h>

#define NN 100000
#define NCLS 40
#define DEGC 16
#define NEDGE (NN*DEGC)
#define ALPHAC 0.2f
#define LPALPHA 0.5f

typedef short short8v __attribute__((ext_vector_type(8)));
typedef float f32x4 __attribute__((ext_vector_type(4)));

__device__ __forceinline__ short f2bf(float f) {
    unsigned u = __float_as_uint(f);
    u += 0x7fff + ((u >> 16) & 1);           // round-to-nearest-even
    return (short)(u >> 16);
}
__device__ __forceinline__ float bf2f(ushort u) {
    return __uint_as_float(((unsigned)u) << 16);
}
__device__ __forceinline__ unsigned char f2e4m3(float f) {
    __hip_fp8_e4m3 e(f);
    return (unsigned char)e.__x;
}
__device__ __forceinline__ void e4m3x4(unsigned u, float* o) {
#pragma unroll
    for (int s = 0; s < 4; ++s) {
        __hip_fp8_e4m3 e;
        e.__x = (__hip_fp8_storage_t)((u >> (8 * s)) & 0xff);
        o[s] = (float)e;
    }
}

// ---------------------------------------------------------------------------
// MFMA GEMM, 512-thread blocks (8 waves, 128 rows/block): LDS 52KB admits
// 2 blocks/CU -> 16 waves/CU (VGPR-capped) vs 12 with 256-thread blocks.
// HASM1: 144 staged B-rows; rows 128..143 = 9th output tile (mini-GEMM,
// PRE-leaky A) -> M1out[rr*32+lr].  Leaky applied after HASM1 MFMAs (NG=1).
// WRT8: fused fp8 copy of C into T8.
// ---------------------------------------------------------------------------
template <int NCH1, bool ABF, bool HASL, bool WRT8, bool HASM1>
__global__ __launch_bounds__(512) void gemm128_lds(
    const void* __restrict__ A1v, const ushort* __restrict__ B1t,
    const ushort* __restrict__ labB64, const ushort* __restrict__ B2t,
    const float* __restrict__ bias, const float* __restrict__ biasm1,
    int leakyA, ushort* __restrict__ C,
    unsigned char* __restrict__ T8, ushort* __restrict__ M1out)
{
    constexpr int K1 = NCH1 * 32;
    constexpr int NG = NCH1 / 4;
    constexpr int NCH = NCH1 + (HASL ? 2 : 0);
    constexpr int BROWS = HASM1 ? 144 : 128;
    constexpr int TOTSLOT = BROWS * 16;              // uint4 slots per K-group
    __shared__ __align__(16) ushort Bs1[BROWS * 128];           // 32/36 KB
    __shared__ __align__(16) ushort Bs2[HASL ? 128 * 64 : 8];   // 16 KB

    const int tid = threadIdx.x;
    const int l   = tid & 63;
    const int w   = tid >> 6;                        // 0..7
    const int lr  = l & 15;
    const int lk8 = (l >> 4) << 3;
    const int n0  = blockIdx.x * 128 + w * 16;
    int r = n0 + lr; r = r < NN ? r : NN - 1;
    const int swz = (lr & 7) << 4;

    short8v afr[NCH];
    if (ABF) {
        const ushort* __restrict__ A = (const ushort*)A1v;
#pragma unroll
        for (int kc = 0; kc < NCH1; ++kc)
            afr[kc] = *(const short8v*)(A + (size_t)r * K1 + kc * 32 + lk8);
    } else {
        const float* __restrict__ A = (const float*)A1v;
#pragma unroll
        for (int g = 0; g < NCH1; g += 2) {
            const float* p0 = A + (size_t)r * K1 + g * 32 + lk8;
            const float* p1 = A + (size_t)r * K1 + (g + 1) * 32 + lk8;
            float4 a0 = *(const float4*)p0;
            float4 a1 = *(const float4*)(p0 + 4);
            float4 b0 = *(const float4*)p1;
            float4 b1 = *(const float4*)(p1 + 4);
            short8v va, vb;
            va[0] = f2bf(a0.x); va[1] = f2bf(a0.y); va[2] = f2bf(a0.z); va[3] = f2bf(a0.w);
            va[4] = f2bf(a1.x); va[5] = f2bf(a1.y); va[6] = f2bf(a1.z); va[7] = f2bf(a1.w);
            vb[0] = f2bf(b0.x); vb[1] = f2bf(b0.y); vb[2] = f2bf(b0.z); vb[3] = f2bf(b0.w);
            vb[4] = f2bf(b1.x); vb[5] = f2bf(b1.y); vb[6] = f2bf(b1.z); vb[7] = f2bf(b1.w);
            afr[g] = va;
            afr[g + 1] = vb;
        }
    }
    if (HASL) {
        afr[NCH1]     = *(const short8v*)(labB64 + (size_t)r * 64 + lk8);
        afr[NCH1 + 1] = *(const short8v*)(labB64 + (size_t)r * 64 + 32 + lk8);
    }

    if (HASL) {
#pragma unroll
        for (int s = 0; s < 2; ++s) {                // 1024 slots / 512 threads
            const int slot = tid + s * 512;
            const int row = slot >> 3, colq = slot & 7;
            uint4 v = *(const uint4*)(B2t + (size_t)row * 64 + colq * 8);
            *(uint4*)((char*)Bs2 + ((row * 128 + colq * 16) ^ ((row & 7) << 4))) = v;
        }
    }

    f32x4 acc[8];
#pragma unroll
    for (int ni = 0; ni < 8; ++ni) acc[ni] = (f32x4){0.f, 0.f, 0.f, 0.f};
    f32x4 accm1 = (f32x4){0.f, 0.f, 0.f, 0.f};

#pragma unroll
    for (int g = 0; g < NG; ++g) {
        if (g) __syncthreads();
#pragma unroll
        for (int s = 0; s < (TOTSLOT + 511) / 512; ++s) {
            const int slot = tid + s * 512;
            if (slot < TOTSLOT) {
                const int row = slot >> 4, colq = slot & 15;
                uint4 v = *(const uint4*)(B1t + (size_t)row * K1 + g * 128 + colq * 8);
                *(uint4*)((char*)Bs1 + ((row * 256 + colq * 16) ^ ((row & 7) << 4))) = v;
            }
        }
        __syncthreads();
        if (HASM1) {                     // 9th tile with PRE-leaky A
#pragma unroll
            for (int kc = 0; kc < 4; ++kc) {
                short8v b = *(const short8v*)((const char*)Bs1 +
                    (((128 + lr) * 256 + kc * 64 + lk8 * 2) ^ swz));
                accm1 = __builtin_amdgcn_mfma_f32_16x16x32_bf16(
                    afr[g * 4 + kc], b, accm1, 0, 0, 0);
            }
        }
        if (ABF && leakyA && g == 0) {
#pragma unroll
            for (int kc = 0; kc < NCH1; ++kc)
#pragma unroll
                for (int j = 0; j < 8; ++j) {
                    float f = bf2f((ushort)afr[kc][j]);
                    f = f > 0.f ? f : ALPHAC * f;
                    afr[kc][j] = f2bf(f);
                }
        }
#pragma unroll
        for (int ni = 0; ni < 8; ++ni) {
#pragma unroll
            for (int kc = 0; kc < 4; ++kc) {
                short8v b = *(const short8v*)((const char*)Bs1 +
                    (((ni * 16 + lr) * 256 + kc * 64 + lk8 * 2) ^ swz));
                acc[ni] = __builtin_amdgcn_mfma_f32_16x16x32_bf16(afr[g * 4 + kc], b, acc[ni], 0, 0, 0);
            }
        }
    }
    if (HASL) {
#pragma unroll
        for (int ni = 0; ni < 8; ++ni) {
#pragma unroll
            for (int kc = 0; kc < 2; ++kc) {
                short8v b = *(const short8v*)((const char*)Bs2 +
                    (((ni * 16 + lr) * 128 + kc * 64 + lk8 * 2) ^ swz));
                acc[ni] = __builtin_amdgcn_mfma_f32_16x16x32_bf16(afr[NCH1 + kc], b, acc[ni], 0, 0, 0);
            }
        }
    }

    const int rsub = (l >> 4) << 2;
#pragma unroll
    for (int ni = 0; ni < 8; ++ni) {
        const int cc = ni * 16 + lr;
        const float bv = bias ? bias[cc] : 0.f;
#pragma unroll
        for (int rg = 0; rg < 4; ++rg) {
            const int rr = n0 + rsub + rg;
            if (rr < NN) {
                const float v = acc[ni][rg] + bv;
                C[(size_t)rr * 128 + cc] = (ushort)f2bf(v);
                if (WRT8) T8[(size_t)rr * 128 + cc] = f2e4m3(v);
            }
        }
    }
    if (HASM1) {
        const float bm = biasm1[lr];
#pragma unroll
        for (int rg = 0; rg < 4; ++rg) {
            const int rr = n0 + rsub + rg;
            if (rr < NN)
                M1out[(size_t)rr * 32 + lr] = (ushort)f2bf(accm1[rg] + bm);
        }
    }
}

// ---------------------------------------------------------------------------
// Aggregation v5: fp8 gather table (128B rows, 2 sectors/row); self row bf16.
// ---------------------------------------------------------------------------
__global__ __launch_bounds__(256) void agg_v5(
    const unsigned char* __restrict__ T8, const ushort* __restrict__ hlin,
    const int* __restrict__ col, const float* __restrict__ sd,
    const float* __restrict__ degree, const float* __restrict__ aggrv,
    const float aggrs, int do_leaky, ushort* __restrict__ hout)
{
    const int lane = threadIdx.x & 63;
    const int node = blockIdx.x * 4 + (threadIdx.x >> 6);
    const int q  = lane >> 4;
    const int cq = lane & 15;

    int cl = 0; float sl = 0.f;
    if (lane < 16) {
        cl = col[node * 16 + lane];
        sl = sd[cl];
    }

    float ax[8];
#pragma unroll
    for (int s = 0; s < 8; ++s) ax[s] = 0.f;

#pragma unroll
    for (int g = 0; g < 4; ++g) {
        const int nb = g * 4 + q;
        const int   c  = __shfl(cl, nb, 64);
        const float wv = __shfl(sl, nb, 64);
        const uint2 u = *(const uint2*)(T8 + (size_t)c * 128 + cq * 8);
        float d0[4], d1[4];
        e4m3x4(u.x, d0);
        e4m3x4(u.y, d1);
#pragma unroll
        for (int s2 = 0; s2 < 4; ++s2) {
            ax[s2]     += wv * d0[s2];
            ax[4 + s2] += wv * d1[s2];
        }
    }
#pragma unroll
    for (int s = 0; s < 8; ++s) {
        ax[s] += __shfl_xor(ax[s], 16, 64);
        ax[s] += __shfl_xor(ax[s], 32, 64);
    }

    const uint4 us = *(const uint4*)(hlin + (size_t)node * 128 + cq * 8);
    const unsigned uus[4] = {us.x, us.y, us.z, us.w};
    const float a = aggrv ? aggrv[node] : aggrs;
    const float d = degree[node];
    uint4 uo;
    unsigned* uop = &uo.x;
#pragma unroll
    for (int s = 0; s < 4; ++s) {
        float ox = a * ax[(s < 2 ? s * 2 : (s - 2) * 2 + 4)] * d;
        float oy = a * ax[(s < 2 ? s * 2 + 1 : (s - 2) * 2 + 5)] * d;
        ox += (1.f - a) * bf2f((ushort)(uus[s] & 0xffff));
        oy += (1.f - a) * bf2f((ushort)(uus[s] >> 16));
        if (do_leaky) {
            ox = ox > 0.f ? ox : ALPHAC * ox;
            oy = oy > 0.f ? oy : ALPHAC * oy;
        }
        uop[s] = (unsigned)(ushort)f2bf(ox) | ((unsigned)(ushort)f2bf(oy) << 16);
    }
    if (q == 0)
        *(uint4*)(hout + (size_t)node * 128 + cq * 8) = uo;
}

// ---------------------------------------------------------------------------
// Fused mini2 + pnode: one neighbor gather computes d2_0/d2_1 (butterfly so
// ALL lanes hold the sums), then per-(node,k) factor precompute inline.
// Writes P0s/P1s (f32) and packed fp8 PK8[N][64]B (m0|PD0|PD1|d2).
// ---------------------------------------------------------------------------
__global__ __launch_bounds__(256) void mini2p(
    const ushort* __restrict__ Mb01, const int* __restrict__ col,
    const float* __restrict__ ab, const float* __restrict__ lf1w,
    const float* __restrict__ lf1b,
    float* __restrict__ P0s, float* __restrict__ P1s,
    unsigned char* __restrict__ PK8)
{
    __shared__ float sm0[16][16][17];
    __shared__ float sm1[16][16][17];
    __shared__ float av0[16][16];
    __shared__ float av1[16][16];
    const int tid = threadIdx.x;
    const int g = tid >> 4, j = tid & 15;
    const int node = blockIdx.x * 16 + g;
    const int c = col[node * 16 + j];
    const ushort* __restrict__ rowp = Mb01 + (size_t)c * 32;
    const uint4 u0 = *(const uint4*)rowp;
    const uint4 u1 = *(const uint4*)(rowp + 8);
    const uint4 u2 = *(const uint4*)(rowp + 16);
    const uint4 u3 = *(const uint4*)(rowp + 24);
    const unsigned w0[8] = {u0.x, u0.y, u0.z, u0.w, u1.x, u1.y, u1.z, u1.w};
    const unsigned w1[8] = {u2.x, u2.y, u2.z, u2.w, u3.x, u3.y, u3.z, u3.w};
#pragma unroll
    for (int s = 0; s < 8; ++s) {
        sm0[g][j][s * 2]     = bf2f((ushort)(w0[s] & 0xffff));
        sm0[g][j][s * 2 + 1] = bf2f((ushort)(w0[s] >> 16));
        sm1[g][j][s * 2]     = bf2f((ushort)(w1[s] & 0xffff));
        sm1[g][j][s * 2 + 1] = bf2f((ushort)(w1[s] >> 16));
    }
    __syncthreads();
    float a0 = 0.f, a1 = 0.f;
#pragma unroll
    for (int nb = 0; nb < 16; ++nb) { a0 += sm0[g][nb][j]; a1 += sm1[g][nb][j]; }
    av0[g][j] = a0 * (1.f / 16.f);
    av1[g][j] = a1 * (1.f / 16.f);
    __syncthreads();
    float dd0 = 1e-12f, dd1 = 1e-12f;
#pragma unroll
    for (int d = 0; d < 16; ++d) {
        float t0 = av0[g][d] - sm0[g][j][d];
        float t1 = av1[g][d] - sm1[g][j][d];
        dd0 += t0 * t0;
        dd1 += t1 * t1;
    }
    float dist0 = sqrtf(dd0), dist1 = sqrtf(dd1);
#pragma unroll
    for (int off = 1; off < 16; off <<= 1) {          // butterfly: all lanes get sum
        dist0 += __shfl_xor(dist0, off, 64);
        dist1 += __shfl_xor(dist1, off, 64);
    }
    const float d2_0 = dist0 * (1.f / 16.f);
    const float d2_1 = dist1 * (1.f / 16.f);

    // ---- fused pnode: this thread handles k=j for node ----
    const int i = node, k = j;
    float m0[17], m1a[17];
    const ushort* r0 = Mb01 + (size_t)i * 32;
    const ushort* r1 = r0 + 16;
#pragma unroll
    for (int d = 0; d < 16; ++d) {
        m0[d]  = bf2f(r0[d]);
        m1a[d] = bf2f(r1[d]) + ab[d];
    }
    m0[16]  = d2_0;
    m1a[16] = d2_1 + ab[16];
    const float* __restrict__ Wk = lf1w + k * 51;
    float p0s = lf1b[k], p1s = p0s, p0d = 0.f, p1d = 0.f;
#pragma unroll
    for (int d = 0; d < 17; ++d) {
        const float w0v = Wk[d], w1v = Wk[17 + d];
        p0s += m0[d]  * w0v;  p0d += m0[d]  * w1v;
        p1s += m1a[d] * w0v;  p1d += m1a[d] * w1v;
    }
    const int idx = i * 16 + k;
    P0s[idx] = p0s;
    P1s[idx] = p1s;
    unsigned char* __restrict__ pk = PK8 + (size_t)i * 64;
    pk[k]      = f2e4m3(m0[k]);
    pk[16 + k] = f2e4m3(p0d);
    pk[32 + k] = f2e4m3(p1d);
    if (k == 0) *(float*)(pk + 48) = d2_0;
}

// ---------------------------------------------------------------------------
// Edge factors: ONE 64B fp8 gather (PK8[c]) per edge; float2 H accumulation;
// fused f1hop reduce.
// ---------------------------------------------------------------------------
__global__ __launch_bounds__(256) void fact2_kernel(
    const unsigned char* __restrict__ PK8,
    const float* __restrict__ P0s, const float* __restrict__ P1s,
    const int* __restrict__ col,
    const float* __restrict__ W2c, const float* __restrict__ lf2w,
    const float* __restrict__ lf2b,
    float* __restrict__ f0out, float* __restrict__ f1hout)
{
    const int e = blockIdx.x * 256 + threadIdx.x;
    const int i = e >> 4;
    const int c = col[e];

    const unsigned char* __restrict__ pki = PK8 + (size_t)i * 64;
    const unsigned char* __restrict__ pkc = PK8 + (size_t)c * 64;
    const uint4 mi8 = *(const uint4*)pki;
    const float d2i = *(const float*)(pki + 48);
    const uint4 mc8 = *(const uint4*)pkc;
    const uint4 p08 = *(const uint4*)(pkc + 16);
    const uint4 p18 = *(const uint4*)(pkc + 32);
    const float d2c = *(const float*)(pkc + 48);

    float mi[16], mc[16], P0d[16], P1d[16];
    e4m3x4(mi8.x, mi);     e4m3x4(mi8.y, mi + 4);
    e4m3x4(mi8.z, mi + 8); e4m3x4(mi8.w, mi + 12);
    e4m3x4(mc8.x, mc);     e4m3x4(mc8.y, mc + 4);
    e4m3x4(mc8.z, mc + 8); e4m3x4(mc8.w, mc + 12);
    e4m3x4(p08.x, P0d);     e4m3x4(p08.y, P0d + 4);
    e4m3x4(p08.z, P0d + 8); e4m3x4(p08.w, P0d + 12);
    e4m3x4(p18.x, P1d);     e4m3x4(p18.y, P1d + 4);
    e4m3x4(p18.z, P1d + 8); e4m3x4(p18.w, P1d + 12);

    float2 H2[8];
#pragma unroll
    for (int k2 = 0; k2 < 8; ++k2) H2[k2] = make_float2(0.f, 0.f);
#pragma unroll
    for (int d = 0; d < 16; ++d) {
        const float hd = fabsf(mc[d] - mi[d]);
        const float2* __restrict__ wv = (const float2*)(W2c + d * 16);
#pragma unroll
        for (int k2 = 0; k2 < 8; ++k2) {
            H2[k2].x = fmaf(hd, wv[k2].x, H2[k2].x);
            H2[k2].y = fmaf(hd, wv[k2].y, H2[k2].y);
        }
    }
    {
        const float hdd = fabsf(d2c - d2i);
        const float2* __restrict__ wv = (const float2*)(W2c + 16 * 16);
#pragma unroll
        for (int k2 = 0; k2 < 8; ++k2) {
            H2[k2].x = fmaf(hdd, wv[k2].x, H2[k2].x);
            H2[k2].y = fmaf(hdd, wv[k2].y, H2[k2].y);
        }
    }
    const float* __restrict__ H = (const float*)H2;

    const float* __restrict__ p0 = P0s + (size_t)i * 16;
    const float* __restrict__ p1 = P1s + (size_t)i * 16;
    float a0 = lf2b[0], a1 = a0;
#pragma unroll
    for (int k = 0; k < 16; ++k) {
        const float t0 = p0[k] + P0d[k] + H[k];
        const float t1 = p1[k] + P1d[k] + H[k];
        const float lw = lf2w[k];
        a0 += (1.f - 2.f / (__expf(2.f * t0) + 1.f)) * lw;
        a1 += (1.f - 2.f / (__expf(2.f * t1) + 1.f)) * lw;
    }
    f0out[e] = 1.f / (1.f + __expf(-a0));
    float f1 = 1.f / (1.f + __expf(-a1));
#pragma unroll
    for (int off = 1; off < 16; off <<= 1) f1 += __shfl_xor(f1, off, 64);
    if ((threadIdx.x & 15) == 0) f1hout[i] = f1 * (1.f / 16.f);
}

__global__ void f2hop_kernel(const float* __restrict__ f0, const float* __restrict__ f1h,
                             const int* __restrict__ col, float* __restrict__ out)
{
    const int i = blockIdx.x * 256 + threadIdx.x;
    if (i >= NN) return;
    float s = 0.f;
#pragma unroll
    for (int t = 0; t < 16; ++t) {
        int e = i * 16 + t;
        s += f0[e] * f1h[col[e]];
    }
    out[i] = s * (1.f / 16.f);
}

// ---------------------------------------------------------------------------
// MFMA logits + fused log_softmax (LDS-staged W).
// ---------------------------------------------------------------------------
__global__ __launch_bounds__(256) void logits_mfma(
    const ushort* __restrict__ X, const ushort* __restrict__ Wb48,
    const float* __restrict__ bias, float* __restrict__ out)
{
    __shared__ __align__(16) ushort Wl[48 * 128];
    const int tid = threadIdx.x;
    const int l  = tid & 63;
    const int w  = tid >> 6;
    const int lr = l & 15;
    const int lk = (l >> 4) << 3;
    const int swz = (lr & 7) << 4;
#pragma unroll
    for (int s = 0; s < 6; ++s) {
        const int slot = tid + s * 256;
        const int row = slot >> 4, colq = slot & 15;
        uint4 v = *(const uint4*)(Wb48 + (size_t)row * 128 + colq * 8);
        *(uint4*)((char*)Wl + ((row * 256 + colq * 16) ^ ((row & 7) << 4))) = v;
    }
    const int row_base = blockIdx.x * 128 + w * 32;
    short8v afr[2][4];
#pragma unroll
    for (int mi = 0; mi < 2; ++mi) {
        int r = row_base + mi * 16 + lr;
        r = r < NN ? r : NN - 1;
#pragma unroll
        for (int kc = 0; kc < 4; ++kc)
            afr[mi][kc] = *(const short8v*)(X + (size_t)r * 128 + kc * 32 + lk);
    }
    __syncthreads();
    f32x4 acc[2][3];
#pragma unroll
    for (int mi = 0; mi < 2; ++mi)
#pragma unroll
        for (int ni = 0; ni < 3; ++ni) acc[mi][ni] = (f32x4){0.f, 0.f, 0.f, 0.f};
#pragma unroll
    for (int ni = 0; ni < 3; ++ni) {
#pragma unroll
        for (int kc = 0; kc < 4; ++kc) {
            short8v b = *(const short8v*)((const char*)Wl +
                (((ni * 16 + lr) * 256 + kc * 64 + lk * 2) ^ swz));
#pragma unroll
            for (int mi = 0; mi < 2; ++mi)
                acc[mi][ni] = __builtin_amdgcn_mfma_f32_16x16x32_bf16(afr[mi][kc], b, acc[mi][ni], 0, 0, 0);
        }
    }

    const float b0 = bias[lr];
    const float b1 = bias[16 + lr];
    const float b2 = (lr < 8) ? bias[32 + lr] : 0.f;
    const int rsub = (l >> 4) << 2;
#pragma unroll
    for (int mi = 0; mi < 2; ++mi) {
#pragma unroll
        for (int reg = 0; reg < 4; ++reg) {
            const int row = row_base + mi * 16 + rsub + reg;
            const float z0 = acc[mi][0][reg] + b0;
            const float z1 = acc[mi][1][reg] + b1;
            const float z2 = (lr < 8) ? acc[mi][2][reg] + b2 : -1e30f;
            float m = fmaxf(fmaxf(z0, z1), z2);
#pragma unroll
            for (int off = 1; off < 16; off <<= 1) m = fmaxf(m, __shfl_xor(m, off, 64));
            float s = __expf(z0 - m) + __expf(z1 - m) + ((lr < 8) ? __expf(z2 - m) : 0.f);
#pragma unroll
            for (int off = 1; off < 16; off <<= 1) s += __shfl_xor(s, off, 64);
            const float lg = m + __logf(s);
            if (row < NN) {
                float* __restrict__ po = out + (size_t)row * NCLS;
                po[lr] = z0 - lg;
                po[16 + lr] = z1 - lg;
                if (lr < 8) po[32 + lr] = z2 - lg;
            }
        }
    }
}

// ---------------------------------------------------------------------------
// Consolidated prep (same as R19).
// ---------------------------------------------------------------------------
__global__ void prep_misc(
    const float* __restrict__ lb_w, const float* __restrict__ lb_b,
    const float* __restrict__ Ws, ushort* __restrict__ WtL1,
    const float* __restrict__ L2F, ushort* __restrict__ W2t,
    const float* __restrict__ la2w, ushort* __restrict__ Wb48,
    const float* __restrict__ lf1w, float* __restrict__ W2c,
    const float* __restrict__ w2m, const float* __restrict__ b2m,
    const float* __restrict__ LPW, const float* __restrict__ degree,
    float* __restrict__ sd2, ushort* __restrict__ B1x,
    float* __restrict__ bias1, float* __restrict__ bm1e)
{
    int b = blockIdx.x;
    const int tid = threadIdx.x;
    if (b < 64) {
        int i = b * 256 + tid;
        int m = i >> 7, k = i & 127;
        WtL1[(size_t)m * 128 + k] = (ushort)f2bf(Ws[32768 + (size_t)k * 128 + m]);
        return;
    }
    b -= 64;
    if (b < 16) {
        int i = b * 256 + tid;
        WtL1[128 * 128 + i] = (ushort)f2bf(w2m[i]);
        return;
    }
    b -= 16;
    if (b < 64) {
        int i = b * 256 + tid;
        int ll = i >> 13, r = i & 8191;
        int m = r >> 6, c = r & 63;
        float acc = 0.f;
        if (c < NCLS) {
            const float* Wl = Ws + (size_t)ll * 32768 + 128 * 128;
            for (int j = 0; j < 128; ++j) acc += L2F[c * 128 + j] * Wl[j * 128 + m];
        }
        W2t[i] = (ushort)f2bf(acc);
        return;
    }
    b -= 64;
    if (b < 24) {
        int i = b * 256 + tid;
        if (i < 48 * 128) {
            int c = i >> 7;
            Wb48[i] = (c < NCLS) ? (ushort)f2bf(la2w[i]) : (ushort)0;
        }
        return;
    }
    b -= 24;
    if (b < 2) {
        int t = b * 256 + tid;
        if (t < 272) {
            int d = t >> 4, k = t & 15;
            W2c[t] = lf1w[k * 51 + 34 + d];
        }
        return;
    }
    b -= 2;
    if (b < 391) {
        int i = b * 256 + tid;
        if (i < NN) sd2[i] = LPW[i] * degree[i];
        return;
    }
    b -= 391;
    if (b < 391) {
        int i = b * 256 + tid;
        if (i < NN) sd2[NN + i] = LPW[NN + i] * degree[i];
        return;
    }
    b -= 391;
    if (b < 128) {
        int i = b * 256 + tid;
        int m = i >> 8, k = i & 255;
        float acc = 0.f;
        for (int mp = 0; mp < 128; ++mp)
            acc += lb_w[mp * 256 + k] * Ws[mp * 128 + m];
        B1x[(size_t)m * 256 + k] = (ushort)f2bf(acc);
        return;
    }
    b -= 128;
    if (b < 16) {
        int i = b * 256 + tid;
        int j = i >> 8, k = i & 255;
        float acc = 0.f;
        for (int mp = 0; mp < 128; ++mp)
            acc += lb_w[mp * 256 + k] * w2m[j * 128 + mp];
        B1x[(size_t)(128 + j) * 256 + k] = (ushort)f2bf(acc);
        return;
    }
    b -= 16;
    {
        if (tid < 128) {
            float acc = 0.f;
            for (int mp = 0; mp < 128; ++mp) acc += lb_b[mp] * Ws[mp * 128 + tid];
            bias1[tid] = acc;
        } else if (tid < 144) {
            const int j = tid - 128;
            float acc = b2m[j];
            for (int mp = 0; mp < 128; ++mp) acc += lb_b[mp] * w2m[j * 128 + mp];
            bm1e[j] = acc;
        }
    }
}

__global__ void cvt_label64v(const float* __restrict__ label, ushort* __restrict__ labB64)
{
    const int idx = blockIdx.x * 256 + threadIdx.x;
    const int i = idx >> 4;
    const int c0 = (idx & 15) * 4;
    ushort o[4];
#pragma unroll
    for (int j = 0; j < 4; ++j) {
        const int c = c0 + j;
        o[j] = (c < NCLS) ? (ushort)f2bf(label[(size_t)i * NCLS + c]) : (ushort)0;
    }
    *(uint2*)(labB64 + (size_t)i * 64 + c0) = make_uint2(
        (unsigned)o[0] | ((unsigned)o[1] << 16),
        (unsigned)o[2] | ((unsigned)o[3] << 16));
}

// ---------------------------------------------------------------------------
extern "C" void kernel_launch(void* const* d_in, const int* in_sizes, int n_in,
                              void* d_out, int out_size, void* d_ws, size_t ws_size,
                              hipStream_t stream)
{
    const float* x      = (const float*)d_in[0];
    const int*   edges  = (const int*)d_in[1];
    const float* degree = (const float*)d_in[2];
    const float* label  = (const float*)d_in[4];
    const float* lb_w   = (const float*)d_in[5];
    const float* lb_b   = (const float*)d_in[6];
    const float* L2F    = (const float*)d_in[7];
    const float* Ws     = (const float*)d_in[8];
    const float* w2m    = (const float*)d_in[9];
    const float* b2m    = (const float*)d_in[10];
    const float* ab     = (const float*)d_in[11];
    const float* lf1w   = (const float*)d_in[12];
    const float* lf1b   = (const float*)d_in[13];
    const float* lf2w   = (const float*)d_in[14];
    const float* lf2b   = (const float*)d_in[15];
    const float* LPW    = (const float*)d_in[16];
    const float* la2w   = (const float*)d_in[17];
    const float* la2b   = (const float*)d_in[18];
    const int* colp = edges + NEDGE;

    float* ws = (float*)d_ws;
    size_t o = 0;
    float* P0sB  = ws + o; o += (size_t)NN * 16;
    float* P1sB  = ws + o; o += (size_t)NN * 16;
    float* f0B   = ws + o; o += NEDGE;
    float* f1hB  = ws + o; o += NN;
    float* aggrB = ws + o; o += NN;
    float* sd2B  = ws + o; o += 2 * NN;
    float* W2cB  = ws + o; o += 272;
    float* bias1B = ws + o; o += 128;
    float* bm1eB  = ws + o; o += 16;
    ushort* bufA = (ushort*)(ws + o); o += (size_t)NN * 128 / 2;
    ushort* bufL = (ushort*)(ws + o); o += (size_t)NN * 128 / 2;
    ushort* labB64 = (ushort*)(ws + o); o += (size_t)NN * 64 / 2;
    ushort* Mb01 = (ushort*)(ws + o); o += (size_t)NN * 32 / 2;
    unsigned char* PK8 = (unsigned char*)(ws + o); o += (size_t)NN * 64 / 4;
    ushort* B1x  = (ushort*)(ws + o); o += 144 * 256 / 2;
    ushort* WtL1 = (ushort*)(ws + o); o += 144 * 128 / 2;
    ushort* W2t  = (ushort*)(ws + o); o += 2 * 128 * 64 / 2;
    ushort* Wb48 = (ushort*)(ws + o); o += 48 * 128 / 2;
    unsigned char* T8 = (unsigned char*)(ws + o); o += (size_t)NN * 128 / 4;

    dim3 b256(256);
    dim3 b512(512);
    // prep: 64+16+64+24+2+391+391+128+16+1 = 1097 blocks
    prep_misc<<<1097, b256, 0, stream>>>(lb_w, lb_b, Ws, WtL1, L2F, W2t, la2w, Wb48,
                                         lf1w, W2cB, w2m, b2m, LPW, degree,
                                         sd2B, B1x, bias1B, bm1eB);
    cvt_label64v<<<6250, b256, 0, stream>>>(label, labB64);

    // ---- layer 0, folded (512-thread blocks, 128 rows each) ----
    gemm128_lds<8, false, true, true, true><<<782, b512, 0, stream>>>(
        x, B1x, labB64, W2t, bias1B, bm1eB, 0, bufL, T8, Mb01 + 16);
    agg_v5<<<25000, b256, 0, stream>>>(T8, bufL, colp, sd2B, degree,
                                       nullptr, LPALPHA, 0, bufA);

    // ---- layer 1 GEMM (moved up): 9th tile = m0 (pre-leaky) ----
    gemm128_lds<4, true, true, true, true><<<782, b512, 0, stream>>>(
        bufA, WtL1, labB64, W2t + 8192, nullptr, b2m, 1, bufL, T8, Mb01);

    // ---- fact chain ----
    mini2p<<<6250, b256, 0, stream>>>(Mb01, colp, ab, lf1w, lf1b, P0sB, P1sB, PK8);
    fact2_kernel<<<6250, b256, 0, stream>>>(PK8, P0sB, P1sB, colp,
                                            W2cB, lf2w, lf2b, f0B, f1hB);
    f2hop_kernel<<<391, b256, 0, stream>>>(f0B, f1hB, colp, aggrB);

    // ---- layer 1 aggregation ----
    agg_v5<<<25000, b256, 0, stream>>>(T8, bufL, colp, sd2B + NN, degree,
                                       aggrB, 0.f, 1, bufA);

    // ---- output ----
    logits_mfma<<<782, b256, 0, stream>>>(bufA, Wb48, la2b, (float*)d_out);
}

// Round 21
// 294.047 us; speedup vs baseline: 1.0411x; 1.0411x over previous
//
#include <hip/hip_runtime.h>
#include <hip/hip_bf16.h>
#include <hip/hip_fp8.h>
#include <math.h>

#define NN 100000
#define NCLS 40
#define DEGC 16
#define NEDGE (NN*DEGC)
#define ALPHAC 0.2f
#define LPALPHA 0.5f

typedef short short8v __attribute__((ext_vector_type(8)));
typedef float f32x4 __attribute__((ext_vector_type(4)));

__device__ __forceinline__ short f2bf(float f) {
    unsigned u = __float_as_uint(f);
    u += 0x7fff + ((u >> 16) & 1);           // round-to-nearest-even
    return (short)(u >> 16);
}
__device__ __forceinline__ float bf2f(ushort u) {
    return __uint_as_float(((unsigned)u) << 16);
}
__device__ __forceinline__ unsigned char f2e4m3(float f) {
    __hip_fp8_e4m3 e(f);
    return (unsigned char)e.__x;
}
__device__ __forceinline__ void e4m3x4(unsigned u, float* o) {
#pragma unroll
    for (int s = 0; s < 4; ++s) {
        __hip_fp8_e4m3 e;
        e.__x = (__hip_fp8_storage_t)((u >> (8 * s)) & 0xff);
        o[s] = (float)e;
    }
}

// ---------------------------------------------------------------------------
// MFMA GEMM (R19-proven 256-thread config).  HASM1: 144 staged B-rows; rows
// 128..143 = 9th output tile (mini-GEMM, PRE-leaky A) -> M1out[rr*32+lr].
// Leaky applied after HASM1 MFMAs of group 0 (valid: leaky only when NG=1).
// C[NN][128](bf16) = A1[NN][K1] @ B1t (+ labB64 @ B2t) (+bias).
// WRT8: fused fp8-e4m3 copy of C into T8.
// ---------------------------------------------------------------------------
template <int NCH1, bool ABF, bool HASL, bool WRT8, bool HASM1>
__global__ __launch_bounds__(256) void gemm128_lds(
    const void* __restrict__ A1v, const ushort* __restrict__ B1t,
    const ushort* __restrict__ labB64, const ushort* __restrict__ B2t,
    const float* __restrict__ bias, const float* __restrict__ biasm1,
    int leakyA, ushort* __restrict__ C,
    unsigned char* __restrict__ T8, ushort* __restrict__ M1out)
{
    constexpr int K1 = NCH1 * 32;
    constexpr int NG = NCH1 / 4;
    constexpr int NCH = NCH1 + (HASL ? 2 : 0);
    constexpr int BROWS = HASM1 ? 144 : 128;
    constexpr int NSLOT = BROWS / 16;
    __shared__ __align__(16) ushort Bs1[BROWS * 128];           // 32/36 KB
    __shared__ __align__(16) ushort Bs2[HASL ? 128 * 64 : 8];   // 16 KB

    const int tid = threadIdx.x;
    const int l   = tid & 63;
    const int w   = tid >> 6;
    const int lr  = l & 15;
    const int lk8 = (l >> 4) << 3;
    const int n0  = blockIdx.x * 64 + w * 16;
    int r = n0 + lr; r = r < NN ? r : NN - 1;
    const int swz = (lr & 7) << 4;

    short8v afr[NCH];
    if (ABF) {
        const ushort* __restrict__ A = (const ushort*)A1v;
#pragma unroll
        for (int kc = 0; kc < NCH1; ++kc)
            afr[kc] = *(const short8v*)(A + (size_t)r * K1 + kc * 32 + lk8);
    } else {
        const float* __restrict__ A = (const float*)A1v;
#pragma unroll
        for (int g = 0; g < NCH1; g += 2) {
            const float* p0 = A + (size_t)r * K1 + g * 32 + lk8;
            const float* p1 = A + (size_t)r * K1 + (g + 1) * 32 + lk8;
            float4 a0 = *(const float4*)p0;
            float4 a1 = *(const float4*)(p0 + 4);
            float4 b0 = *(const float4*)p1;
            float4 b1 = *(const float4*)(p1 + 4);
            short8v va, vb;
            va[0] = f2bf(a0.x); va[1] = f2bf(a0.y); va[2] = f2bf(a0.z); va[3] = f2bf(a0.w);
            va[4] = f2bf(a1.x); va[5] = f2bf(a1.y); va[6] = f2bf(a1.z); va[7] = f2bf(a1.w);
            vb[0] = f2bf(b0.x); vb[1] = f2bf(b0.y); vb[2] = f2bf(b0.z); vb[3] = f2bf(b0.w);
            vb[4] = f2bf(b1.x); vb[5] = f2bf(b1.y); vb[6] = f2bf(b1.z); vb[7] = f2bf(b1.w);
            afr[g] = va;
            afr[g + 1] = vb;
        }
    }
    if (HASL) {
        afr[NCH1]     = *(const short8v*)(labB64 + (size_t)r * 64 + lk8);
        afr[NCH1 + 1] = *(const short8v*)(labB64 + (size_t)r * 64 + 32 + lk8);
    }

    if (HASL) {
#pragma unroll
        for (int s = 0; s < 4; ++s) {
            const int slot = tid + s * 256;
            const int row = slot >> 3, colq = slot & 7;
            uint4 v = *(const uint4*)(B2t + (size_t)row * 64 + colq * 8);
            *(uint4*)((char*)Bs2 + ((row * 128 + colq * 16) ^ ((row & 7) << 4))) = v;
        }
    }

    f32x4 acc[8];
#pragma unroll
    for (int ni = 0; ni < 8; ++ni) acc[ni] = (f32x4){0.f, 0.f, 0.f, 0.f};
    f32x4 accm1 = (f32x4){0.f, 0.f, 0.f, 0.f};

#pragma unroll
    for (int g = 0; g < NG; ++g) {
        if (g) __syncthreads();
#pragma unroll
        for (int s = 0; s < NSLOT; ++s) {
            const int slot = tid + s * 256;
            const int row = slot >> 4, colq = slot & 15;
            uint4 v = *(const uint4*)(B1t + (size_t)row * K1 + g * 128 + colq * 8);
            *(uint4*)((char*)Bs1 + ((row * 256 + colq * 16) ^ ((row & 7) << 4))) = v;
        }
        __syncthreads();
        if (HASM1) {                     // 9th tile with PRE-leaky A
#pragma unroll
            for (int kc = 0; kc < 4; ++kc) {
                short8v b = *(const short8v*)((const char*)Bs1 +
                    (((128 + lr) * 256 + kc * 64 + lk8 * 2) ^ swz));
                accm1 = __builtin_amdgcn_mfma_f32_16x16x32_bf16(
                    afr[g * 4 + kc], b, accm1, 0, 0, 0);
            }
        }
        if (ABF && leakyA && g == 0) {   // apply leaky once (NG=1 when leaky)
#pragma unroll
            for (int kc = 0; kc < NCH1; ++kc)
#pragma unroll
                for (int j = 0; j < 8; ++j) {
                    float f = bf2f((ushort)afr[kc][j]);
                    f = f > 0.f ? f : ALPHAC * f;
                    afr[kc][j] = f2bf(f);
                }
        }
#pragma unroll
        for (int ni = 0; ni < 8; ++ni) {
#pragma unroll
            for (int kc = 0; kc < 4; ++kc) {
                short8v b = *(const short8v*)((const char*)Bs1 +
                    (((ni * 16 + lr) * 256 + kc * 64 + lk8 * 2) ^ swz));
                acc[ni] = __builtin_amdgcn_mfma_f32_16x16x32_bf16(afr[g * 4 + kc], b, acc[ni], 0, 0, 0);
            }
        }
    }
    if (HASL) {
#pragma unroll
        for (int ni = 0; ni < 8; ++ni) {
#pragma unroll
            for (int kc = 0; kc < 2; ++kc) {
                short8v b = *(const short8v*)((const char*)Bs2 +
                    (((ni * 16 + lr) * 128 + kc * 64 + lk8 * 2) ^ swz));
                acc[ni] = __builtin_amdgcn_mfma_f32_16x16x32_bf16(afr[NCH1 + kc], b, acc[ni], 0, 0, 0);
            }
        }
    }

    const int rsub = (l >> 4) << 2;
#pragma unroll
    for (int ni = 0; ni < 8; ++ni) {
        const int cc = ni * 16 + lr;
        const float bv = bias ? bias[cc] : 0.f;
#pragma unroll
        for (int rg = 0; rg < 4; ++rg) {
            const int rr = n0 + rsub + rg;
            if (rr < NN) {
                const float v = acc[ni][rg] + bv;
                C[(size_t)rr * 128 + cc] = (ushort)f2bf(v);
                if (WRT8) T8[(size_t)rr * 128 + cc] = f2e4m3(v);
            }
        }
    }
    if (HASM1) {
        const float bm = biasm1[lr];
#pragma unroll
        for (int rg = 0; rg < 4; ++rg) {
            const int rr = n0 + rsub + rg;
            if (rr < NN)
                M1out[(size_t)rr * 32 + lr] = (ushort)f2bf(accm1[rg] + bm);
        }
    }
}

// ---------------------------------------------------------------------------
// Aggregation v5: fp8 gather table (128B rows, 2 sectors/row); self row bf16.
// ---------------------------------------------------------------------------
__global__ __launch_bounds__(256) void agg_v5(
    const unsigned char* __restrict__ T8, const ushort* __restrict__ hlin,
    const int* __restrict__ col, const float* __restrict__ sd,
    const float* __restrict__ degree, const float* __restrict__ aggrv,
    const float aggrs, int do_leaky, ushort* __restrict__ hout)
{
    const int lane = threadIdx.x & 63;
    const int node = blockIdx.x * 4 + (threadIdx.x >> 6);
    const int q  = lane >> 4;
    const int cq = lane & 15;

    int cl = 0; float sl = 0.f;
    if (lane < 16) {
        cl = col[node * 16 + lane];
        sl = sd[cl];
    }

    float ax[8];
#pragma unroll
    for (int s = 0; s < 8; ++s) ax[s] = 0.f;

#pragma unroll
    for (int g = 0; g < 4; ++g) {
        const int nb = g * 4 + q;
        const int   c  = __shfl(cl, nb, 64);
        const float wv = __shfl(sl, nb, 64);
        const uint2 u = *(const uint2*)(T8 + (size_t)c * 128 + cq * 8);
        float d0[4], d1[4];
        e4m3x4(u.x, d0);
        e4m3x4(u.y, d1);
#pragma unroll
        for (int s2 = 0; s2 < 4; ++s2) {
            ax[s2]     += wv * d0[s2];
            ax[4 + s2] += wv * d1[s2];
        }
    }
#pragma unroll
    for (int s = 0; s < 8; ++s) {
        ax[s] += __shfl_xor(ax[s], 16, 64);
        ax[s] += __shfl_xor(ax[s], 32, 64);
    }

    const uint4 us = *(const uint4*)(hlin + (size_t)node * 128 + cq * 8);
    const unsigned uus[4] = {us.x, us.y, us.z, us.w};
    const float a = aggrv ? aggrv[node] : aggrs;
    const float d = degree[node];
    uint4 uo;
    unsigned* uop = &uo.x;
#pragma unroll
    for (int s = 0; s < 4; ++s) {
        float ox = a * ax[(s < 2 ? s * 2 : (s - 2) * 2 + 4)] * d;
        float oy = a * ax[(s < 2 ? s * 2 + 1 : (s - 2) * 2 + 5)] * d;
        ox += (1.f - a) * bf2f((ushort)(uus[s] & 0xffff));
        oy += (1.f - a) * bf2f((ushort)(uus[s] >> 16));
        if (do_leaky) {
            ox = ox > 0.f ? ox : ALPHAC * ox;
            oy = oy > 0.f ? oy : ALPHAC * oy;
        }
        uop[s] = (unsigned)(ushort)f2bf(ox) | ((unsigned)(ushort)f2bf(oy) << 16);
    }
    if (q == 0)
        *(uint4*)(hout + (size_t)node * 128 + cq * 8) = uo;
}

// ---------------------------------------------------------------------------
// Fused mini2 + pnode (R20-proven): one neighbor gather computes d2 via
// butterfly (all lanes hold the sum), then per-(node,k) factor precompute.
// Writes P0s/P1s (f32) and packed fp8 PK8[N][64]B (m0|PD0|PD1|d2).
// ---------------------------------------------------------------------------
__global__ __launch_bounds__(256) void mini2p(
    const ushort* __restrict__ Mb01, const int* __restrict__ col,
    const float* __restrict__ ab, const float* __restrict__ lf1w,
    const float* __restrict__ lf1b,
    float* __restrict__ P0s, float* __restrict__ P1s,
    unsigned char* __restrict__ PK8)
{
    __shared__ float sm0[16][16][17];
    __shared__ float sm1[16][16][17];
    __shared__ float av0[16][16];
    __shared__ float av1[16][16];
    const int tid = threadIdx.x;
    const int g = tid >> 4, j = tid & 15;
    const int node = blockIdx.x * 16 + g;
    const int c = col[node * 16 + j];
    const ushort* __restrict__ rowp = Mb01 + (size_t)c * 32;
    const uint4 u0 = *(const uint4*)rowp;
    const uint4 u1 = *(const uint4*)(rowp + 8);
    const uint4 u2 = *(const uint4*)(rowp + 16);
    const uint4 u3 = *(const uint4*)(rowp + 24);
    const unsigned w0[8] = {u0.x, u0.y, u0.z, u0.w, u1.x, u1.y, u1.z, u1.w};
    const unsigned w1[8] = {u2.x, u2.y, u2.z, u2.w, u3.x, u3.y, u3.z, u3.w};
#pragma unroll
    for (int s = 0; s < 8; ++s) {
        sm0[g][j][s * 2]     = bf2f((ushort)(w0[s] & 0xffff));
        sm0[g][j][s * 2 + 1] = bf2f((ushort)(w0[s] >> 16));
        sm1[g][j][s * 2]     = bf2f((ushort)(w1[s] & 0xffff));
        sm1[g][j][s * 2 + 1] = bf2f((ushort)(w1[s] >> 16));
    }
    __syncthreads();
    float a0 = 0.f, a1 = 0.f;
#pragma unroll
    for (int nb = 0; nb < 16; ++nb) { a0 += sm0[g][nb][j]; a1 += sm1[g][nb][j]; }
    av0[g][j] = a0 * (1.f / 16.f);
    av1[g][j] = a1 * (1.f / 16.f);
    __syncthreads();
    float dd0 = 1e-12f, dd1 = 1e-12f;
#pragma unroll
    for (int d = 0; d < 16; ++d) {
        float t0 = av0[g][d] - sm0[g][j][d];
        float t1 = av1[g][d] - sm1[g][j][d];
        dd0 += t0 * t0;
        dd1 += t1 * t1;
    }
    float dist0 = sqrtf(dd0), dist1 = sqrtf(dd1);
#pragma unroll
    for (int off = 1; off < 16; off <<= 1) {
        dist0 += __shfl_xor(dist0, off, 64);
        dist1 += __shfl_xor(dist1, off, 64);
    }
    const float d2_0 = dist0 * (1.f / 16.f);
    const float d2_1 = dist1 * (1.f / 16.f);

    const int i = node, k = j;
    float m0[17], m1a[17];
    const ushort* r0 = Mb01 + (size_t)i * 32;
    const ushort* r1 = r0 + 16;
#pragma unroll
    for (int d = 0; d < 16; ++d) {
        m0[d]  = bf2f(r0[d]);
        m1a[d] = bf2f(r1[d]) + ab[d];
    }
    m0[16]  = d2_0;
    m1a[16] = d2_1 + ab[16];
    const float* __restrict__ Wk = lf1w + k * 51;
    float p0s = lf1b[k], p1s = p0s, p0d = 0.f, p1d = 0.f;
#pragma unroll
    for (int d = 0; d < 17; ++d) {
        const float w0v = Wk[d], w1v = Wk[17 + d];
        p0s += m0[d]  * w0v;  p0d += m0[d]  * w1v;
        p1s += m1a[d] * w0v;  p1d += m1a[d] * w1v;
    }
    const int idx = i * 16 + k;
    P0s[idx] = p0s;
    P1s[idx] = p1s;
    unsigned char* __restrict__ pk = PK8 + (size_t)i * 64;
    pk[k]      = f2e4m3(m0[k]);
    pk[16 + k] = f2e4m3(p0d);
    pk[32 + k] = f2e4m3(p1d);
    if (k == 0) *(float*)(pk + 48) = d2_0;
}

// ---------------------------------------------------------------------------
// Edge factors: ONE 64B fp8 gather (PK8[c]) per edge; float2 H accumulation;
// fused f1hop reduce.
// ---------------------------------------------------------------------------
__global__ __launch_bounds__(256) void fact2_kernel(
    const unsigned char* __restrict__ PK8,
    const float* __restrict__ P0s, const float* __restrict__ P1s,
    const int* __restrict__ col,
    const float* __restrict__ W2c, const float* __restrict__ lf2w,
    const float* __restrict__ lf2b,
    float* __restrict__ f0out, float* __restrict__ f1hout)
{
    const int e = blockIdx.x * 256 + threadIdx.x;
    const int i = e >> 4;
    const int c = col[e];

    const unsigned char* __restrict__ pki = PK8 + (size_t)i * 64;
    const unsigned char* __restrict__ pkc = PK8 + (size_t)c * 64;
    const uint4 mi8 = *(const uint4*)pki;
    const float d2i = *(const float*)(pki + 48);
    const uint4 mc8 = *(const uint4*)pkc;
    const uint4 p08 = *(const uint4*)(pkc + 16);
    const uint4 p18 = *(const uint4*)(pkc + 32);
    const float d2c = *(const float*)(pkc + 48);

    float mi[16], mc[16], P0d[16], P1d[16];
    e4m3x4(mi8.x, mi);     e4m3x4(mi8.y, mi + 4);
    e4m3x4(mi8.z, mi + 8); e4m3x4(mi8.w, mi + 12);
    e4m3x4(mc8.x, mc);     e4m3x4(mc8.y, mc + 4);
    e4m3x4(mc8.z, mc + 8); e4m3x4(mc8.w, mc + 12);
    e4m3x4(p08.x, P0d);     e4m3x4(p08.y, P0d + 4);
    e4m3x4(p08.z, P0d + 8); e4m3x4(p08.w, P0d + 12);
    e4m3x4(p18.x, P1d);     e4m3x4(p18.y, P1d + 4);
    e4m3x4(p18.z, P1d + 8); e4m3x4(p18.w, P1d + 12);

    float2 H2[8];
#pragma unroll
    for (int k2 = 0; k2 < 8; ++k2) H2[k2] = make_float2(0.f, 0.f);
#pragma unroll
    for (int d = 0; d < 16; ++d) {
        const float hd = fabsf(mc[d] - mi[d]);
        const float2* __restrict__ wv = (const float2*)(W2c + d * 16);
#pragma unroll
        for (int k2 = 0; k2 < 8; ++k2) {
            H2[k2].x = fmaf(hd, wv[k2].x, H2[k2].x);
            H2[k2].y = fmaf(hd, wv[k2].y, H2[k2].y);
        }
    }
    {
        const float hdd = fabsf(d2c - d2i);
        const float2* __restrict__ wv = (const float2*)(W2c + 16 * 16);
#pragma unroll
        for (int k2 = 0; k2 < 8; ++k2) {
            H2[k2].x = fmaf(hdd, wv[k2].x, H2[k2].x);
            H2[k2].y = fmaf(hdd, wv[k2].y, H2[k2].y);
        }
    }
    const float* __restrict__ H = (const float*)H2;

    const float* __restrict__ p0 = P0s + (size_t)i * 16;
    const float* __restrict__ p1 = P1s + (size_t)i * 16;
    float a0 = lf2b[0], a1 = a0;
#pragma unroll
    for (int k = 0; k < 16; ++k) {
        const float t0 = p0[k] + P0d[k] + H[k];
        const float t1 = p1[k] + P1d[k] + H[k];
        const float lw = lf2w[k];
        a0 += (1.f - 2.f / (__expf(2.f * t0) + 1.f)) * lw;
        a1 += (1.f - 2.f / (__expf(2.f * t1) + 1.f)) * lw;
    }
    f0out[e] = 1.f / (1.f + __expf(-a0));
    float f1 = 1.f / (1.f + __expf(-a1));
#pragma unroll
    for (int off = 1; off < 16; off <<= 1) f1 += __shfl_xor(f1, off, 64);
    if ((threadIdx.x & 15) == 0) f1hout[i] = f1 * (1.f / 16.f);
}

__global__ void f2hop_kernel(const float* __restrict__ f0, const float* __restrict__ f1h,
                             const int* __restrict__ col, float* __restrict__ out)
{
    const int i = blockIdx.x * 256 + threadIdx.x;
    if (i >= NN) return;
    float s = 0.f;
#pragma unroll
    for (int t = 0; t < 16; ++t) {
        int e = i * 16 + t;
        s += f0[e] * f1h[col[e]];
    }
    out[i] = s * (1.f / 16.f);
}

// ---------------------------------------------------------------------------
// MFMA logits + fused log_softmax (LDS-staged W).
// ---------------------------------------------------------------------------
__global__ __launch_bounds__(256) void logits_mfma(
    const ushort* __restrict__ X, const ushort* __restrict__ Wb48,
    const float* __restrict__ bias, float* __restrict__ out)
{
    __shared__ __align__(16) ushort Wl[48 * 128];
    const int tid = threadIdx.x;
    const int l  = tid & 63;
    const int w  = tid >> 6;
    const int lr = l & 15;
    const int lk = (l >> 4) << 3;
    const int swz = (lr & 7) << 4;
#pragma unroll
    for (int s = 0; s < 6; ++s) {
        const int slot = tid + s * 256;
        const int row = slot >> 4, colq = slot & 15;
        uint4 v = *(const uint4*)(Wb48 + (size_t)row * 128 + colq * 8);
        *(uint4*)((char*)Wl + ((row * 256 + colq * 16) ^ ((row & 7) << 4))) = v;
    }
    const int row_base = blockIdx.x * 128 + w * 32;
    short8v afr[2][4];
#pragma unroll
    for (int mi = 0; mi < 2; ++mi) {
        int r = row_base + mi * 16 + lr;
        r = r < NN ? r : NN - 1;
#pragma unroll
        for (int kc = 0; kc < 4; ++kc)
            afr[mi][kc] = *(const short8v*)(X + (size_t)r * 128 + kc * 32 + lk);
    }
    __syncthreads();
    f32x4 acc[2][3];
#pragma unroll
    for (int mi = 0; mi < 2; ++mi)
#pragma unroll
        for (int ni = 0; ni < 3; ++ni) acc[mi][ni] = (f32x4){0.f, 0.f, 0.f, 0.f};
#pragma unroll
    for (int ni = 0; ni < 3; ++ni) {
#pragma unroll
        for (int kc = 0; kc < 4; ++kc) {
            short8v b = *(const short8v*)((const char*)Wl +
                (((ni * 16 + lr) * 256 + kc * 64 + lk * 2) ^ swz));
#pragma unroll
            for (int mi = 0; mi < 2; ++mi)
                acc[mi][ni] = __builtin_amdgcn_mfma_f32_16x16x32_bf16(afr[mi][kc], b, acc[mi][ni], 0, 0, 0);
        }
    }

    const float b0 = bias[lr];
    const float b1 = bias[16 + lr];
    const float b2 = (lr < 8) ? bias[32 + lr] : 0.f;
    const int rsub = (l >> 4) << 2;
#pragma unroll
    for (int mi = 0; mi < 2; ++mi) {
#pragma unroll
        for (int reg = 0; reg < 4; ++reg) {
            const int row = row_base + mi * 16 + rsub + reg;
            const float z0 = acc[mi][0][reg] + b0;
            const float z1 = acc[mi][1][reg] + b1;
            const float z2 = (lr < 8) ? acc[mi][2][reg] + b2 : -1e30f;
            float m = fmaxf(fmaxf(z0, z1), z2);
#pragma unroll
            for (int off = 1; off < 16; off <<= 1) m = fmaxf(m, __shfl_xor(m, off, 64));
            float s = __expf(z0 - m) + __expf(z1 - m) + ((lr < 8) ? __expf(z2 - m) : 0.f);
#pragma unroll
            for (int off = 1; off < 16; off <<= 1) s += __shfl_xor(s, off, 64);
            const float lg = m + __logf(s);
            if (row < NN) {
                float* __restrict__ po = out + (size_t)row * NCLS;
                po[lr] = z0 - lg;
                po[16 + lr] = z1 - lg;
                if (lr < 8) po[32 + lr] = z2 - lg;
            }
        }
    }
}

// ---------------------------------------------------------------------------
// Consolidated prep (R19 form).
// ---------------------------------------------------------------------------
__global__ void prep_misc(
    const float* __restrict__ lb_w, const float* __restrict__ lb_b,
    const float* __restrict__ Ws, ushort* __restrict__ WtL1,
    const float* __restrict__ L2F, ushort* __restrict__ W2t,
    const float* __restrict__ la2w, ushort* __restrict__ Wb48,
    const float* __restrict__ lf1w, float* __restrict__ W2c,
    const float* __restrict__ w2m, const float* __restrict__ b2m,
    const float* __restrict__ LPW, const float* __restrict__ degree,
    float* __restrict__ sd2, ushort* __restrict__ B1x,
    float* __restrict__ bias1, float* __restrict__ bm1e)
{
    int b = blockIdx.x;
    const int tid = threadIdx.x;
    if (b < 64) {
        int i = b * 256 + tid;
        int m = i >> 7, k = i & 127;
        WtL1[(size_t)m * 128 + k] = (ushort)f2bf(Ws[32768 + (size_t)k * 128 + m]);
        return;
    }
    b -= 64;
    if (b < 16) {
        int i = b * 256 + tid;
        WtL1[128 * 128 + i] = (ushort)f2bf(w2m[i]);
        return;
    }
    b -= 16;
    if (b < 64) {
        int i = b * 256 + tid;
        int ll = i >> 13, r = i & 8191;
        int m = r >> 6, c = r & 63;
        float acc = 0.f;
        if (c < NCLS) {
            const float* Wl = Ws + (size_t)ll * 32768 + 128 * 128;
            for (int j = 0; j < 128; ++j) acc += L2F[c * 128 + j] * Wl[j * 128 + m];
        }
        W2t[i] = (ushort)f2bf(acc);
        return;
    }
    b -= 64;
    if (b < 24) {
        int i = b * 256 + tid;
        if (i < 48 * 128) {
            int c = i >> 7;
            Wb48[i] = (c < NCLS) ? (ushort)f2bf(la2w[i]) : (ushort)0;
        }
        return;
    }
    b -= 24;
    if (b < 2) {
        int t = b * 256 + tid;
        if (t < 272) {
            int d = t >> 4, k = t & 15;
            W2c[t] = lf1w[k * 51 + 34 + d];
        }
        return;
    }
    b -= 2;
    if (b < 391) {
        int i = b * 256 + tid;
        if (i < NN) sd2[i] = LPW[i] * degree[i];
        return;
    }
    b -= 391;
    if (b < 391) {
        int i = b * 256 + tid;
        if (i < NN) sd2[NN + i] = LPW[NN + i] * degree[i];
        return;
    }
    b -= 391;
    if (b < 128) {
        int i = b * 256 + tid;
        int m = i >> 8, k = i & 255;
        float acc = 0.f;
        for (int mp = 0; mp < 128; ++mp)
            acc += lb_w[mp * 256 + k] * Ws[mp * 128 + m];
        B1x[(size_t)m * 256 + k] = (ushort)f2bf(acc);
        return;
    }
    b -= 128;
    if (b < 16) {
        int i = b * 256 + tid;
        int j = i >> 8, k = i & 255;
        float acc = 0.f;
        for (int mp = 0; mp < 128; ++mp)
            acc += lb_w[mp * 256 + k] * w2m[j * 128 + mp];
        B1x[(size_t)(128 + j) * 256 + k] = (ushort)f2bf(acc);
        return;
    }
    b -= 16;
    {
        if (tid < 128) {
            float acc = 0.f;
            for (int mp = 0; mp < 128; ++mp) acc += lb_b[mp] * Ws[mp * 128 + tid];
            bias1[tid] = acc;
        } else if (tid < 144) {
            const int j = tid - 128;
            float acc = b2m[j];
            for (int mp = 0; mp < 128; ++mp) acc += lb_b[mp] * w2m[j * 128 + mp];
            bm1e[j] = acc;
        }
    }
}

__global__ void cvt_label64v(const float* __restrict__ label, ushort* __restrict__ labB64)
{
    const int idx = blockIdx.x * 256 + threadIdx.x;
    const int i = idx >> 4;
    const int c0 = (idx & 15) * 4;
    ushort o[4];
#pragma unroll
    for (int j = 0; j < 4; ++j) {
        const int c = c0 + j;
        o[j] = (c < NCLS) ? (ushort)f2bf(label[(size_t)i * NCLS + c]) : (ushort)0;
    }
    *(uint2*)(labB64 + (size_t)i * 64 + c0) = make_uint2(
        (unsigned)o[0] | ((unsigned)o[1] << 16),
        (unsigned)o[2] | ((unsigned)o[3] << 16));
}

// ---------------------------------------------------------------------------
extern "C" void kernel_launch(void* const* d_in, const int* in_sizes, int n_in,
                              void* d_out, int out_size, void* d_ws, size_t ws_size,
                              hipStream_t stream)
{
    const float* x      = (const float*)d_in[0];
    const int*   edges  = (const int*)d_in[1];
    const float* degree = (const float*)d_in[2];
    const float* label  = (const float*)d_in[4];
    const float* lb_w   = (const float*)d_in[5];
    const float* lb_b   = (const float*)d_in[6];
    const float* L2F    = (const float*)d_in[7];
    const float* Ws     = (const float*)d_in[8];
    const float* w2m    = (const float*)d_in[9];
    const float* b2m    = (const float*)d_in[10];
    const float* ab     = (const float*)d_in[11];
    const float* lf1w   = (const float*)d_in[12];
    const float* lf1b   = (const float*)d_in[13];
    const float* lf2w   = (const float*)d_in[14];
    const float* lf2b   = (const float*)d_in[15];
    const float* LPW    = (const float*)d_in[16];
    const float* la2w   = (const float*)d_in[17];
    const float* la2b   = (const float*)d_in[18];
    const int* colp = edges + NEDGE;

    float* ws = (float*)d_ws;
    size_t o = 0;
    float* P0sB  = ws + o; o += (size_t)NN * 16;
    float* P1sB  = ws + o; o += (size_t)NN * 16;
    float* f0B   = ws + o; o += NEDGE;
    float* f1hB  = ws + o; o += NN;
    float* aggrB = ws + o; o += NN;
    float* sd2B  = ws + o; o += 2 * NN;
    float* W2cB  = ws + o; o += 272;
    float* bias1B = ws + o; o += 128;
    float* bm1eB  = ws + o; o += 16;
    ushort* bufA = (ushort*)(ws + o); o += (size_t)NN * 128 / 2;
    ushort* bufL = (ushort*)(ws + o); o += (size_t)NN * 128 / 2;
    ushort* labB64 = (ushort*)(ws + o); o += (size_t)NN * 64 / 2;
    ushort* Mb01 = (ushort*)(ws + o); o += (size_t)NN * 32 / 2;
    unsigned char* PK8 = (unsigned char*)(ws + o); o += (size_t)NN * 64 / 4;
    ushort* B1x  = (ushort*)(ws + o); o += 144 * 256 / 2;
    ushort* WtL1 = (ushort*)(ws + o); o += 144 * 128 / 2;
    ushort* W2t  = (ushort*)(ws + o); o += 2 * 128 * 64 / 2;
    ushort* Wb48 = (ushort*)(ws + o); o += 48 * 128 / 2;
    unsigned char* T8 = (unsigned char*)(ws + o); o += (size_t)NN * 128 / 4;

    dim3 b256(256);
    // prep: 64+16+64+24+2+391+391+128+16+1 = 1097 blocks
    prep_misc<<<1097, b256, 0, stream>>>(lb_w, lb_b, Ws, WtL1, L2F, W2t, la2w, Wb48,
                                         lf1w, W2cB, w2m, b2m, LPW, degree,
                                         sd2B, B1x, bias1B, bm1eB);
    cvt_label64v<<<6250, b256, 0, stream>>>(label, labB64);

    // ---- layer 0, folded (256-thread blocks, R19 config) ----
    gemm128_lds<8, false, true, true, true><<<1563, b256, 0, stream>>>(
        x, B1x, labB64, W2t, bias1B, bm1eB, 0, bufL, T8, Mb01 + 16);
    agg_v5<<<25000, b256, 0, stream>>>(T8, bufL, colp, sd2B, degree,
                                       nullptr, LPALPHA, 0, bufA);

    // ---- layer 1 GEMM (moved up): 9th tile = m0 (pre-leaky) ----
    gemm128_lds<4, true, true, true, true><<<1563, b256, 0, stream>>>(
        bufA, WtL1, labB64, W2t + 8192, nullptr, b2m, 1, bufL, T8, Mb01);

    // ---- fact chain ----
    mini2p<<<6250, b256, 0, stream>>>(Mb01, colp, ab, lf1w, lf1b, P0sB, P1sB, PK8);
    fact2_kernel<<<6250, b256, 0, stream>>>(PK8, P0sB, P1sB, colp,
                                            W2cB, lf2w, lf2b, f0B, f1hB);
    f2hop_kernel<<<391, b256, 0, stream>>>(f0B, f1hB, colp, aggrB);

    // ---- layer 1 aggregation ----
    agg_v5<<<25000, b256, 0, stream>>>(T8, bufL, colp, sd2B + NN, degree,
                                       aggrB, 0.f, 1, bufA);

    // ---- output ----
    logits_mfma<<<782, b256, 0, stream>>>(bufA, Wb48, la2b, (float*)d_out);
}